// Round 1
// baseline (85.070 us; speedup 1.0000x reference)
//
#include <hip/hip_runtime.h>

// Problem constants (from reference setup_inputs): B=4096, L=128, D=64, V=1000
#define LSEQ 128
#define DIM  64
#define VOC  1000
#define NCNT 129   // counts range 0..128

// G[c][d] = sum_k relu(c*W1[k] + b1[k]) * W2[k][d]
__global__ void build_table_kernel(const float* __restrict__ W1,
                                   const float* __restrict__ b1,
                                   const float* __restrict__ W2,
                                   float* __restrict__ G) {
    const int c = blockIdx.x;   // 0..128
    const int d = threadIdx.x;  // 0..63
    const float fc = (float)c;
    float acc = 0.0f;
#pragma unroll
    for (int k = 0; k < DIM; ++k) {
        float h = fmaf(fc, W1[k], b1[k]);
        h = fmaxf(h, 0.0f);
        acc = fmaf(h, W2[k * DIM + d], acc);
    }
    G[c * DIM + d] = acc;
}

// One block per batch row. 256 threads = 4 groups of 64 lanes:
//   group (sel,half): sel=0 -> src output, sel=1 -> dst output; half = which
//   64 positions of L it accumulates. Lane = output dim d.
__global__ __launch_bounds__(256) void gae_kernel(
        const int* __restrict__ src_ids,
        const int* __restrict__ dst_ids,
        const float* __restrict__ G,
        const float* __restrict__ b2,
        float* __restrict__ out,
        int B) {
    __shared__ int   hist_s[VOC];
    __shared__ int   hist_d[VOC];
    __shared__ int   cnt[4][LSEQ];   // c_ss, c_sd, c_ds, c_dd
    __shared__ float scale[LSEQ];
    __shared__ float red[2][DIM];

    const int b   = blockIdx.x;
    const int tid = threadIdx.x;

    for (int i = tid; i < VOC; i += 256) { hist_s[i] = 0; hist_d[i] = 0; }
    if (tid < LSEQ) scale[tid] = expf((float)(tid - LSEQ));  // w[l] = e^(l-128)
    __syncthreads();

    int sid = 0, did = 0;
    if (tid < LSEQ) {
        sid = src_ids[(size_t)b * LSEQ + tid];
        did = dst_ids[(size_t)b * LSEQ + tid];
        sid = min(max(sid, 0), VOC - 1);
        did = min(max(did, 0), VOC - 1);
        atomicAdd(&hist_s[sid], 1);
        atomicAdd(&hist_d[did], 1);
    }
    __syncthreads();
    if (tid < LSEQ) {
        // padding (id==0) -> count forced to 0 (feature becomes G[0], matching ref)
        cnt[0][tid] = sid ? hist_s[sid] : 0;
        cnt[1][tid] = sid ? hist_d[sid] : 0;
        cnt[2][tid] = did ? hist_s[did] : 0;
        cnt[3][tid] = did ? hist_d[did] : 0;
    }
    __syncthreads();

    const int d    = tid & (DIM - 1);
    const int sel  = (tid >> 6) & 1;   // 0 = src_feat, 1 = dst_feat
    const int half = tid >> 7;         // which half of the sequence
    const int* cA = cnt[sel * 2 + 0];
    const int* cB = cnt[sel * 2 + 1];

    float acc = 0.0f;
#pragma unroll 8
    for (int i = 0; i < LSEQ / 2; ++i) {
        const int l  = half * (LSEQ / 2) + i;
        const float wl = scale[l];
        const int c0 = cA[l];
        const int c1 = cB[l];
        const float g0 = G[c0 * DIM + d];  // lanes d=0..63: coalesced 256B
        const float g1 = G[c1 * DIM + d];
        acc = fmaf(wl, g0 + g1, acc);
    }

    if (half == 1) red[sel][d] = acc;
    __syncthreads();
    if (half == 0) {
        // 1 / sum_{l=0..127} e^(l-128) = (e-1)/(1-e^-128) ~= e-1
        const float invW = 1.7182818284590452f;
        const float tot  = (acc + red[sel][d]) * invW + 2.0f * b2[d];
        out[(size_t)sel * B * DIM + (size_t)b * DIM + d] = tot;
    }
}

extern "C" void kernel_launch(void* const* d_in, const int* in_sizes, int n_in,
                              void* d_out, int out_size, void* d_ws, size_t ws_size,
                              hipStream_t stream) {
    const int*   src_ids = (const int*)d_in[0];
    const int*   dst_ids = (const int*)d_in[1];
    const float* W1      = (const float*)d_in[2];
    const float* b1      = (const float*)d_in[3];
    const float* W2      = (const float*)d_in[4];
    const float* b2      = (const float*)d_in[5];
    float*       out     = (float*)d_out;
    float*       G       = (float*)d_ws;   // 129*64*4 = 33 KB, rebuilt every call

    const int B = in_sizes[0] / LSEQ;

    build_table_kernel<<<NCNT, DIM, 0, stream>>>(W1, b1, W2, G);
    gae_kernel<<<B, 256, 0, stream>>>(src_ids, dst_ids, G, b2, out, B);
}

// Round 2
// 74.876 us; speedup vs baseline: 1.1361x; 1.1361x over previous
//
#include <hip/hip_runtime.h>

// Problem constants (from reference setup_inputs): B=4096, L=128, D=64, V=1000
#define LSEQ   128
#define DIM    64
#define VOC    1000
#define NCNT   129   // counts range 0..128
#define HWORDS 250   // histogram packed as 4 byte-counters per uint32 (1000 ids)
#define TAIL   32    // positions kept in the weighted sum: w[l]=e^(l-128), l<96 -> <=e^-32 (fp32-invisible)

// G[c][d] = sum_k relu(c*W1[k] + b1[k]) * W2[k][d]
__global__ void build_table_kernel(const float* __restrict__ W1,
                                   const float* __restrict__ b1,
                                   const float* __restrict__ W2,
                                   float* __restrict__ G) {
    const int c = blockIdx.x;   // 0..128
    const int d = threadIdx.x;  // 0..63
    const float fc = (float)c;
    float acc = 0.0f;
#pragma unroll
    for (int k = 0; k < DIM; ++k) {
        float h = fmaf(fc, W1[k], b1[k]);
        h = fmaxf(h, 0.0f);
        acc = fmaf(h, W2[k * DIM + d], acc);
    }
    G[c * DIM + d] = acc;
}

// One block per batch row. 256 threads = 4 wave-groups of 64 lanes (lane = dim d):
//   group g: sel = g&1 (0 -> src output, 1 -> dst output), part = g>>1
//   (which 16 of the TAIL positions it accumulates).
__global__ __launch_bounds__(256) void gae_kernel(
        const int* __restrict__ src_ids,
        const int* __restrict__ dst_ids,
        const float* __restrict__ G,
        const float* __restrict__ b2,
        float* __restrict__ out,
        int B) {
    __shared__ unsigned int hs[HWORDS];   // byte-packed: count(id) = (hs[id>>2]>>((id&3)*8))&255
    __shared__ unsigned int hd[HWORDS];
    __shared__ int   ids_s[LSEQ];
    __shared__ int   ids_d[LSEQ];
    __shared__ float red[2][DIM];

    const int b   = blockIdx.x;
    const int tid = threadIdx.x;

    if (tid < HWORDS) { hs[tid] = 0u; hd[tid] = 0u; }
    __syncthreads();

    // histogram needs ALL 128 ids per table; counts <=128 fit a byte, no carry-out
    const int p = tid & (LSEQ - 1);
    if (tid < LSEQ) {
        const int v = src_ids[(size_t)b * LSEQ + p];
        ids_s[p] = v;
        atomicAdd(&hs[v >> 2], 1u << ((v & 3) * 8));
    } else {
        const int v = dst_ids[(size_t)b * LSEQ + p];
        ids_d[p] = v;
        atomicAdd(&hd[v >> 2], 1u << ((v & 3) * 8));
    }
    __syncthreads();

    const int d    = tid & (DIM - 1);
    const int g    = tid >> 6;
    const int sel  = g & 1;         // 0 = src_feat, 1 = dst_feat
    const int part = g >> 1;        // which 16 tail positions
    const int l0   = LSEQ - TAIL + part * (TAIL / 2);
    const int* __restrict__ myids = sel ? ids_d : ids_s;

    float w   = expf((float)(l0 - LSEQ));   // e^(l-128), running product below
    float acc = 0.0f;
#pragma unroll
    for (int i = 0; i < TAIL / 2; ++i) {
        const int l = l0 + i;
        const int v = myids[l];                 // wave-uniform -> broadcast ds_read
        const unsigned sh = (unsigned)(v & 3) * 8u;
        // padding (id==0) -> count forced to 0 (feature = G[0], matching ref mask)
        const int c0 = v ? (int)((hs[v >> 2] >> sh) & 255u) : 0;
        const int c1 = v ? (int)((hd[v >> 2] >> sh) & 255u) : 0;
        const float g0 = G[c0 * DIM + d];       // 64 lanes x 4B contiguous, L1/L2-hit
        const float g1 = G[c1 * DIM + d];
        acc = fmaf(w, g0 + g1, acc);
        w *= 2.71828182845904523f;
    }

    if (part == 1) red[sel][d] = acc;
    __syncthreads();
    if (part == 0) {
        // 1 / sum_{l=0..127} e^(l-128) = (e-1)/(1-e^-128) == e-1 in fp32
        const float invW = 1.71828182845904523f;
        out[(size_t)sel * B * DIM + (size_t)b * DIM + d] =
            (acc + red[sel][d]) * invW + 2.0f * b2[d];
    }
}

extern "C" void kernel_launch(void* const* d_in, const int* in_sizes, int n_in,
                              void* d_out, int out_size, void* d_ws, size_t ws_size,
                              hipStream_t stream) {
    const int*   src_ids = (const int*)d_in[0];
    const int*   dst_ids = (const int*)d_in[1];
    const float* W1      = (const float*)d_in[2];
    const float* b1      = (const float*)d_in[3];
    const float* W2      = (const float*)d_in[4];
    const float* b2      = (const float*)d_in[5];
    float*       out     = (float*)d_out;
    float*       G       = (float*)d_ws;   // 129*64*4 = 33 KB, rebuilt every call

    const int B = in_sizes[0] / LSEQ;

    build_table_kernel<<<NCNT, DIM, 0, stream>>>(W1, b1, W2, G);
    gae_kernel<<<B, 256, 0, stream>>>(src_ids, dst_ids, G, b2, out, B);
}

// Round 3
// 71.997 us; speedup vs baseline: 1.1816x; 1.0400x over previous
//
#include <hip/hip_runtime.h>

// Problem constants (from reference setup_inputs): B=4096, L=128, D=64, V=1000
#define LSEQ 128
#define DIM  64
#define NCNT 129   // counts range 0..128
#define TAIL 16    // w[l]=e^(l-128); dropping l<112 leaves error <= e^-16*2*max|G| ~ 1e-4

// G[c][d] = sum_k relu(c*W1[k] + b1[k]) * W2[k][d]
// 33 blocks x 256 threads; wave w of block blk handles c = blk*4 + w.
__global__ __launch_bounds__(256) void build_table_kernel(
        const float* __restrict__ W1,
        const float* __restrict__ b1,
        const float* __restrict__ W2,
        float* __restrict__ G) {
    const int c = blockIdx.x * 4 + (threadIdx.x >> 6);
    const int d = threadIdx.x & (DIM - 1);
    if (c >= NCNT) return;
    const float fc = (float)c;
    float acc = 0.0f;
#pragma unroll
    for (int k = 0; k < DIM; ++k) {
        float h = fmaxf(fmaf(fc, W1[k], b1[k]), 0.0f);
        acc = fmaf(h, W2[k * DIM + d], acc);
    }
    G[c * DIM + d] = acc;
}

// One block per batch row. 256 threads = 4 waves (lane = output dim d):
//   wave g: sel = g&1 (0 -> src output, 1 -> dst output), part = g>>1
//   (which 8 of the TAIL positions it accumulates).
// Counting is ballot-based: lane j of every wave holds ids[j] and ids[j+64]
// of both lists in registers; count(v) = popc(ballot(lo==v)) + popc(ballot(hi==v)).
__global__ __launch_bounds__(256) void gae_kernel(
        const int* __restrict__ src_ids,
        const int* __restrict__ dst_ids,
        const float* __restrict__ G,
        const float* __restrict__ b2,
        float* __restrict__ out,
        int B) {
    __shared__ float red[2][DIM];

    const int b    = blockIdx.x;
    const int lane = threadIdx.x & 63;
    const int g    = threadIdx.x >> 6;
    const int sel  = g & 1;      // 0 = src_feat, 1 = dst_feat
    const int part = g >> 1;     // which 8 tail positions

    const int* __restrict__ sp = src_ids + (size_t)b * LSEQ;
    const int* __restrict__ dp = dst_ids + (size_t)b * LSEQ;
    // redundant across waves -> L1 hits; removes LDS staging + a __syncthreads
    const int s_lo = sp[lane];
    const int s_hi = sp[lane + 64];
    const int d_lo = dp[lane];
    const int d_hi = dp[lane + 64];
    const int my_hi = sel ? d_hi : s_hi;   // tail positions 112..127 live here

    const int l0 = LSEQ - TAIL + part * (TAIL / 2);   // 112 or 120
    float w   = expf((float)(l0 - LSEQ));             // e^(l-128), running product
    float acc = 0.0f;
#pragma unroll
    for (int i = 0; i < TAIL / 2; ++i) {
        const int l = l0 + i;
        const int v = __shfl(my_hi, l - 64, 64);      // wave-uniform tail id
        // count of v across all 128 positions of each list
        int c0 = __popcll(__ballot(s_lo == v)) + __popcll(__ballot(s_hi == v));
        int c1 = __popcll(__ballot(d_lo == v)) + __popcll(__ballot(d_hi == v));
        if (v == 0) { c0 = 0; c1 = 0; }               // padding mask (ref semantics)
        const float g0 = G[c0 * DIM + lane];          // 256B contiguous, L1-hit
        const float g1 = G[c1 * DIM + lane];
        acc = fmaf(w, g0 + g1, acc);
        w *= 2.71828182845904523f;
    }

    if (part == 1) red[sel][lane] = acc;
    __syncthreads();
    if (part == 0) {
        // 1 / sum_{l=0..127} e^(l-128) == e-1 in fp32
        const float invW = 1.71828182845904523f;
        out[(size_t)sel * B * DIM + (size_t)b * DIM + lane] =
            (acc + red[sel][lane]) * invW + 2.0f * b2[lane];
    }
}

extern "C" void kernel_launch(void* const* d_in, const int* in_sizes, int n_in,
                              void* d_out, int out_size, void* d_ws, size_t ws_size,
                              hipStream_t stream) {
    const int*   src_ids = (const int*)d_in[0];
    const int*   dst_ids = (const int*)d_in[1];
    const float* W1      = (const float*)d_in[2];
    const float* b1      = (const float*)d_in[3];
    const float* W2      = (const float*)d_in[4];
    const float* b2      = (const float*)d_in[5];
    float*       out     = (float*)d_out;
    float*       G       = (float*)d_ws;   // 129*64*4 = 33 KB, rebuilt every call

    const int B = in_sizes[0] / LSEQ;

    build_table_kernel<<<(NCNT + 3) / 4, 256, 0, stream>>>(W1, b1, W2, G);
    gae_kernel<<<B, 256, 0, stream>>>(src_ids, dst_ids, G, b2, out, B);
}

// Round 4
// 71.743 us; speedup vs baseline: 1.1858x; 1.0035x over previous
//
#include <hip/hip_runtime.h>

// Problem constants (from reference setup_inputs): B=4096, L=128, D=64, V=1000
#define LSEQ 128
#define DIM  64
#define NCNT 129   // counts range 0..128
#define TAIL 16    // w[l]=e^(l-128); dropping l<112 leaves error <= e^-16*2*max|G| ~ 1e-4

// G[c][d] = sum_k relu(c*W1[k] + b1[k]) * W2[k][d]
// 33 blocks x 256 threads; wave w of block blk handles c = blk*4 + w.
__global__ __launch_bounds__(256) void build_table_kernel(
        const float* __restrict__ W1,
        const float* __restrict__ b1,
        const float* __restrict__ W2,
        float* __restrict__ G) {
    const int c = blockIdx.x * 4 + (threadIdx.x >> 6);
    const int d = threadIdx.x & (DIM - 1);
    if (c >= NCNT) return;
    const float fc = (float)c;
    float acc = 0.0f;
#pragma unroll
    for (int k = 0; k < DIM; ++k) {
        float h = fmaxf(fmaf(fc, W1[k], b1[k]), 0.0f);
        acc = fmaf(h, W2[k * DIM + d], acc);
    }
    G[c * DIM + d] = acc;
}

// 2 rows per block, 4 waves; each wave owns one (row, sel) output end-to-end:
//   wave g: row = 2*blockIdx.x + (g>>1), sel = g&1 (0 -> src_feat, 1 -> dst_feat)
// No LDS, no __syncthreads. Counting is ballot-based: lane j holds ids[j] and
// ids[j+64] of both lists; count(v) = popc(ballot(lo==v)) + popc(ballot(hi==v)).
__global__ __launch_bounds__(256) void gae_kernel(
        const int* __restrict__ src_ids,
        const int* __restrict__ dst_ids,
        const float* __restrict__ G,
        const float* __restrict__ b2,
        float* __restrict__ out,
        int B) {
    const int lane = threadIdx.x & 63;
    const int g    = threadIdx.x >> 6;
    const int sel  = g & 1;                      // 0 = src_feat, 1 = dst_feat
    const int row  = blockIdx.x * 2 + (g >> 1);
    if (row >= B) return;

    const int* __restrict__ sp = src_ids + (size_t)row * LSEQ;
    const int* __restrict__ dp = dst_ids + (size_t)row * LSEQ;
    // redundant across waves -> L1 hits
    const int s_lo = sp[lane];
    const int s_hi = sp[lane + 64];
    const int d_lo = dp[lane];
    const int d_hi = dp[lane + 64];
    const int my_hi = sel ? d_hi : s_hi;         // tail positions 112..127 live here

    float w   = expf((float)-TAIL);              // e^(l0-128), running product below
    float acc = 0.0f;
#pragma unroll
    for (int i = 0; i < TAIL; ++i) {
        const int l = LSEQ - TAIL + i;
        const int v = __shfl(my_hi, l - 64, 64); // wave-uniform tail id
        // count of v across all 128 positions of each list
        int c0 = __popcll(__ballot(s_lo == v)) + __popcll(__ballot(s_hi == v));
        int c1 = __popcll(__ballot(d_lo == v)) + __popcll(__ballot(d_hi == v));
        if (v == 0) { c0 = 0; c1 = 0; }          // padding mask (ref semantics)
        const float g0 = G[c0 * DIM + lane];     // 256B contiguous, L1-hit
        const float g1 = G[c1 * DIM + lane];
        acc = fmaf(w, g0 + g1, acc);
        w *= 2.71828182845904523f;
    }

    // 1 / sum_{l=0..127} e^(l-128) == e-1 in fp32
    const float invW = 1.71828182845904523f;
    out[(size_t)sel * B * DIM + (size_t)row * DIM + lane] =
        acc * invW + 2.0f * b2[lane];
}

extern "C" void kernel_launch(void* const* d_in, const int* in_sizes, int n_in,
                              void* d_out, int out_size, void* d_ws, size_t ws_size,
                              hipStream_t stream) {
    const int*   src_ids = (const int*)d_in[0];
    const int*   dst_ids = (const int*)d_in[1];
    const float* W1      = (const float*)d_in[2];
    const float* b1      = (const float*)d_in[3];
    const float* W2      = (const float*)d_in[4];
    const float* b2      = (const float*)d_in[5];
    float*       out     = (float*)d_out;
    float*       G       = (float*)d_ws;   // 129*64*4 = 33 KB, rebuilt every call

    const int B = in_sizes[0] / LSEQ;

    build_table_kernel<<<(NCNT + 3) / 4, 256, 0, stream>>>(W1, b1, W2, G);
    gae_kernel<<<(B + 1) / 2, 256, 0, stream>>>(src_ids, dst_ids, G, b2, out, B);
}